// Round 7
// baseline (5191.442 us; speedup 1.0000x reference)
//
#include <hip/hip_runtime.h>
#include <hip/hip_bf16.h>

// Problem constants
#define EMBD   1024
#define NHEAD  16
#define HDIM   64
#define SEQ    2048
#define BATCH  2
#define MROWS  4096          // BATCH*SEQ
#define NQKV   3072          // 3*EMBD

// ---------------------------------------------------------------------------
// Kernel 1: qkv = x @ w_qkv (fp32), fused RoPE epilogue.
// Writes q (scaled by 1/8), k, v as fp32 in (B,H,S,D) layout.
// ---------------------------------------------------------------------------
__global__ __launch_bounds__(256) void gemm_qkv_rope(
    const float* __restrict__ x,     // (4096,1024)
    const float* __restrict__ w,     // (1024,3072)
    float* __restrict__ qws, float* __restrict__ kws, float* __restrict__ vws)
{
    __shared__ float As[16][68];   // As[k][m], padded
    __shared__ float Bs[16][68];   // Bs[k][n], padded

    const int t  = threadIdx.x;
    const int tx = t & 15;
    const int ty = t >> 4;
    const int n0 = blockIdx.x * 64;
    const int m0 = blockIdx.y * 64;

    const int arow = t >> 2;
    const int acg  = (t & 3) * 4;
    const int brow = t >> 4;
    const int bcg  = (t & 15) * 4;

    float acc[4][4] = {};

    for (int k0 = 0; k0 < EMBD; k0 += 16) {
        float4 a4 = *(const float4*)(x + (size_t)(m0 + arow) * EMBD + k0 + acg);
        As[acg + 0][arow] = a4.x;
        As[acg + 1][arow] = a4.y;
        As[acg + 2][arow] = a4.z;
        As[acg + 3][arow] = a4.w;
        float4 b4 = *(const float4*)(w + (size_t)(k0 + brow) * NQKV + n0 + bcg);
        *(float4*)&Bs[brow][bcg] = b4;
        __syncthreads();
        #pragma unroll
        for (int kk = 0; kk < 16; ++kk) {
            float4 a = *(const float4*)&As[kk][ty * 4];
            float4 b = *(const float4*)&Bs[kk][tx * 4];
            float av[4] = {a.x, a.y, a.z, a.w};
            float bv[4] = {b.x, b.y, b.z, b.w};
            #pragma unroll
            for (int i = 0; i < 4; ++i)
                #pragma unroll
                for (int j = 0; j < 4; ++j)
                    acc[i][j] += av[i] * bv[j];
        }
        __syncthreads();
    }

    const float LOG1E4_OVER_32 = 9.210340371976184f / 32.0f;  // ln(10000)/32
    const int nbase = n0 + tx * 4;
    const int which = nbase >> 10;
    const int h     = (nbase >> 6) & 15;
    const int dbase = nbase & 63;

    #pragma unroll
    for (int i = 0; i < 4; ++i) {
        int m = m0 + ty * 4 + i;
        int b = m >> 11;
        int s = m & 2047;
        size_t rowoff = ((size_t)(b * NHEAD + h) * SEQ + s) * HDIM;
        if (which == 2) {
            #pragma unroll
            for (int j = 0; j < 4; ++j) vws[rowoff + dbase + j] = acc[i][j];
        } else {
            float* dst = (which == 0) ? qws : kws;
            float scale = (which == 0) ? 0.125f : 1.0f;   // D^-0.5 folded into q
            #pragma unroll
            for (int c = 0; c < 4; c += 2) {
                int de = dbase + c;
                // emb = concat([freqs,freqs]) -> freq index = d & 31
                float fe = __expf(-(float)(de & 31) * LOG1E4_OVER_32);
                float fo = __expf(-(float)((de + 1) & 31) * LOG1E4_OVER_32);
                float se, ce, so, co;
                sincosf((float)s * fe, &se, &ce);
                sincosf((float)s * fo, &so, &co);
                float qe = acc[i][c], qo = acc[i][c + 1];
                // out[2t]   = x[2t]*cos[2t]     - x[2t+1]*sin[2t]
                // out[2t+1] = x[2t+1]*cos[2t+1] + x[2t]*sin[2t+1]
                dst[rowoff + de]     = (qe * ce - qo * se) * scale;
                dst[rowoff + de + 1] = (qo * co + qe * so) * scale;
            }
        }
    }
}

// ---------------------------------------------------------------------------
// Kernel 2: COMPLEMENT-masked attention (reference semantics!).
// Reference keeps scores where attend = ~allowed | (j>i), i.e. it EXCLUDES
// exactly the sparse-causal set  P_i = [0, min(4,i+1)) ∪ [max(4,L_i), i],
//   L_i = max(0, min(i-128, (i>>8)<<8)).
// One wave per query row; all 2048 keys scored; excluded ones set to -1e30.
// q pre-scaled by 1/8.  Output (B,S,E) fp32.
// ---------------------------------------------------------------------------
__global__ __launch_bounds__(256) void attn_kernel(
    const float* __restrict__ qws, const float* __restrict__ kws,
    const float* __restrict__ vws, float* __restrict__ attn)
{
    __shared__ float qrow[4][64];
    __shared__ float sc[4][SEQ];    // 32 KB

    const int wave = threadIdx.x >> 6;
    const int lane = threadIdx.x & 63;
    const int R  = blockIdx.x * 4 + wave;   // [0, B*H*S)
    const int bh = R >> 11;                 // b*16 + h
    const int i  = R & 2047;                // query position

    const size_t base = (size_t)bh * SEQ * HDIM;
    const float* kp = kws + base;
    const float* vp = vws + base;

    qrow[wave][lane] = qws[base + (size_t)i * HDIM + lane];

    // excluded interval parameters
    int nglob = (i + 1 < 4) ? (i + 1) : 4;          // [0, nglob) excluded
    int L = (i - 128 < ((i >> 8) << 8)) ? (i - 128) : ((i >> 8) << 8);
    if (L < 0) L = 0;
    int j0 = (L > 4) ? L : 4;                       // [j0, i] excluded (dead if j0>i)

    __syncthreads();

    // scores for ALL 2048 keys; excluded -> -1e30
    for (int c = 0; c < SEQ / 64; ++c) {
        int j = c * 64 + lane;
        const float* kr = kp + (size_t)j * HDIM;
        float s = 0.f;
        #pragma unroll
        for (int d4 = 0; d4 < HDIM; d4 += 4) {
            float4 kq = *(const float4*)(kr + d4);
            float4 qq = *(const float4*)&qrow[wave][d4];
            s += qq.x * kq.x + qq.y * kq.y + qq.z * kq.z + qq.w * kq.w;
        }
        bool excl = (j < nglob) || (j >= j0 && j <= i);
        sc[wave][j] = excl ? -1e30f : s;
    }
    __syncthreads();

    // softmax over the row
    float mx = -1e30f;
    for (int tt = lane; tt < SEQ; tt += 64) mx = fmaxf(mx, sc[wave][tt]);
    #pragma unroll
    for (int o = 32; o; o >>= 1) mx = fmaxf(mx, __shfl_xor(mx, o));
    float sum = 0.f;
    for (int tt = lane; tt < SEQ; tt += 64) {
        float p = __expf(sc[wave][tt] - mx);   // masked: exp(-huge) = 0
        sc[wave][tt] = p;
        sum += p;
    }
    #pragma unroll
    for (int o = 32; o; o >>= 1) sum += __shfl_xor(sum, o);
    float inv = 1.0f / sum;
    __syncthreads();

    // PV over all keys (masked keys have p = 0)
    float a0 = 0.f, a1 = 0.f, a2 = 0.f, a3 = 0.f;
    for (int tt = 0; tt < SEQ; tt += 4) {
        a0 += sc[wave][tt + 0] * vp[(size_t)(tt + 0) * HDIM + lane];
        a1 += sc[wave][tt + 1] * vp[(size_t)(tt + 1) * HDIM + lane];
        a2 += sc[wave][tt + 2] * vp[(size_t)(tt + 2) * HDIM + lane];
        a3 += sc[wave][tt + 3] * vp[(size_t)(tt + 3) * HDIM + lane];
    }
    float acc = (a0 + a1) + (a2 + a3);
    int b = bh >> 4, h = bh & 15;
    attn[((size_t)(b * SEQ + i)) * EMBD + h * HDIM + lane] = acc * inv;
}

// ---------------------------------------------------------------------------
// Kernel 3: out = attn (fp32 4096x1024) @ w_out (fp32 1024x1024) -> fp32
// ---------------------------------------------------------------------------
__global__ __launch_bounds__(256) void gemm_out(
    const float* __restrict__ A,
    const float* __restrict__ w,
    float* __restrict__ out)
{
    __shared__ float As[16][68];
    __shared__ float Bs[16][68];

    const int t  = threadIdx.x;
    const int tx = t & 15;
    const int ty = t >> 4;
    const int n0 = blockIdx.x * 64;
    const int m0 = blockIdx.y * 64;

    const int arow = t >> 2;
    const int acg  = (t & 3) * 4;
    const int brow = t >> 4;
    const int bcg  = (t & 15) * 4;

    float acc[4][4] = {};

    for (int k0 = 0; k0 < EMBD; k0 += 16) {
        float4 a4 = *(const float4*)(A + (size_t)(m0 + arow) * EMBD + k0 + acg);
        As[acg + 0][arow] = a4.x;
        As[acg + 1][arow] = a4.y;
        As[acg + 2][arow] = a4.z;
        As[acg + 3][arow] = a4.w;
        float4 b4 = *(const float4*)(w + (size_t)(k0 + brow) * EMBD + n0 + bcg);
        *(float4*)&Bs[brow][bcg] = b4;
        __syncthreads();
        #pragma unroll
        for (int kk = 0; kk < 16; ++kk) {
            float4 a = *(const float4*)&As[kk][ty * 4];
            float4 b = *(const float4*)&Bs[kk][tx * 4];
            float av[4] = {a.x, a.y, a.z, a.w};
            float bv[4] = {b.x, b.y, b.z, b.w};
            #pragma unroll
            for (int i = 0; i < 4; ++i)
                #pragma unroll
                for (int j = 0; j < 4; ++j)
                    acc[i][j] += av[i] * bv[j];
        }
        __syncthreads();
    }

    #pragma unroll
    for (int i = 0; i < 4; ++i) {
        int m = m0 + ty * 4 + i;
        float4 o;
        o.x = acc[i][0]; o.y = acc[i][1]; o.z = acc[i][2]; o.w = acc[i][3];
        *(float4*)(out + (size_t)m * EMBD + n0 + tx * 4) = o;
    }
}

// ---------------------------------------------------------------------------
extern "C" void kernel_launch(void* const* d_in, const int* in_sizes, int n_in,
                              void* d_out, int out_size, void* d_ws, size_t ws_size,
                              hipStream_t stream) {
    const float* x     = (const float*)d_in[0];  // (2,2048,1024)
    const float* w_qkv = (const float*)d_in[1];  // (1024,3072)
    const float* w_out = (const float*)d_in[2];  // (1024,1024)
    float* out = (float*)d_out;                  // (2,2048,1024)

    // 64 MB fp32 workspace (R2 ran this footprint without incident).
    float* ws  = (float*)d_ws;
    float* qws = ws;                    // (B,H,S,D) 16 MB
    float* kws = ws + 4194304;
    float* vws = ws + 8388608;
    float* aws = ws + 12582912;         // (B,S,E) 16 MB

    dim3 blk(256);
    dim3 g1(NQKV / 64, MROWS / 64);     // (48, 64)
    gemm_qkv_rope<<<g1, blk, 0, stream>>>(x, w_qkv, qws, kws, vws);

    attn_kernel<<<dim3((BATCH * NHEAD * SEQ) / 4), blk, 0, stream>>>(qws, kws, vws, aws);

    dim3 g2(EMBD / 64, MROWS / 64);     // (16, 64)
    gemm_out<<<g2, blk, 0, stream>>>(aws, w_out, out);
}

// Round 8
// 755.604 us; speedup vs baseline: 6.8706x; 6.8706x over previous
//
#include <hip/hip_runtime.h>
#include <hip/hip_bf16.h>

// Problem constants
#define EMBD   1024
#define NHEAD  16
#define HDIM   64
#define SEQ    2048
#define BATCH  2
#define MROWS  4096          // BATCH*SEQ
#define NQKV   3072          // 3*EMBD

using floatx4 = __attribute__((ext_vector_type(4))) float;
using short8  = __attribute__((ext_vector_type(8))) short;

static __device__ __forceinline__ float bf2f(unsigned short u) {
    unsigned int v = ((unsigned int)u) << 16;
    return __uint_as_float(v);
}
static __device__ __forceinline__ unsigned short f2bf(float f) {
    __hip_bfloat16 h = __float2bfloat16(f);   // RNE
    return *reinterpret_cast<unsigned short*>(&h);
}

// ---------------------------------------------------------------------------
// Kernel 1: qkv = x @ w_qkv (fp32 math), fused RoPE epilogue.
// Emits bf16: q (scaled 1/8) and k as [bh][s][d]; V TRANSPOSED as [bh][d][s].
// ---------------------------------------------------------------------------
__global__ __launch_bounds__(256) void gemm_qkv_rope(
    const float* __restrict__ x,     // (4096,1024)
    const float* __restrict__ w,     // (1024,3072)
    unsigned short* __restrict__ qst,
    unsigned short* __restrict__ kst,
    unsigned short* __restrict__ vtT)
{
    __shared__ float As[16][68];
    __shared__ float Bs[16][68];

    const int t  = threadIdx.x;
    const int tx = t & 15;
    const int ty = t >> 4;
    const int n0 = blockIdx.x * 64;
    const int m0 = blockIdx.y * 64;

    const int arow = t >> 2;
    const int acg  = (t & 3) * 4;
    const int brow = t >> 4;
    const int bcg  = (t & 15) * 4;

    float acc[4][4] = {};

    for (int k0 = 0; k0 < EMBD; k0 += 16) {
        float4 a4 = *(const float4*)(x + (size_t)(m0 + arow) * EMBD + k0 + acg);
        As[acg + 0][arow] = a4.x;
        As[acg + 1][arow] = a4.y;
        As[acg + 2][arow] = a4.z;
        As[acg + 3][arow] = a4.w;
        float4 b4 = *(const float4*)(w + (size_t)(k0 + brow) * NQKV + n0 + bcg);
        *(float4*)&Bs[brow][bcg] = b4;
        __syncthreads();
        #pragma unroll
        for (int kk = 0; kk < 16; ++kk) {
            float4 a = *(const float4*)&As[kk][ty * 4];
            float4 b = *(const float4*)&Bs[kk][tx * 4];
            float av[4] = {a.x, a.y, a.z, a.w};
            float bv[4] = {b.x, b.y, b.z, b.w};
            #pragma unroll
            for (int i = 0; i < 4; ++i)
                #pragma unroll
                for (int j = 0; j < 4; ++j)
                    acc[i][j] += av[i] * bv[j];
        }
        __syncthreads();
    }

    const float LOG1E4_OVER_32 = 9.210340371976184f / 32.0f;  // ln(10000)/32
    const int nbase = n0 + tx * 4;
    const int which = nbase >> 10;
    const int h     = (nbase >> 6) & 15;
    const int dbase = nbase & 63;

    #pragma unroll
    for (int i = 0; i < 4; ++i) {
        int m = m0 + ty * 4 + i;
        int b = m >> 11;
        int s = m & 2047;
        int bh = b * NHEAD + h;
        if (which == 2) {
            // V transposed: vtT[bh][d][s]
            #pragma unroll
            for (int j = 0; j < 4; ++j)
                vtT[((size_t)bh * HDIM + dbase + j) * SEQ + s] = f2bf(acc[i][j]);
        } else {
            unsigned short* dst = (which == 0) ? qst : kst;
            float scale = (which == 0) ? 0.125f : 1.0f;   // D^-0.5 folded into q
            float r[4];
            #pragma unroll
            for (int c = 0; c < 4; c += 2) {
                int de = dbase + c;
                float fe = __expf(-(float)(de & 31) * LOG1E4_OVER_32);
                float fo = __expf(-(float)((de + 1) & 31) * LOG1E4_OVER_32);
                float se, ce, so, co;
                sincosf((float)s * fe, &se, &ce);
                sincosf((float)s * fo, &so, &co);
                float qe = acc[i][c], qo = acc[i][c + 1];
                r[c]     = (qe * ce - qo * se) * scale;
                r[c + 1] = (qo * co + qe * so) * scale;
            }
            ushort4 o;
            o.x = f2bf(r[0]); o.y = f2bf(r[1]); o.z = f2bf(r[2]); o.w = f2bf(r[3]);
            *(ushort4*)(dst + ((size_t)bh * SEQ + s) * HDIM + dbase) = o;
        }
    }
}

// ---------------------------------------------------------------------------
// Kernel 2: complement-masked attention via bf16 MFMA, single pass.
// Excluded set P_i = [0, min(4,i+1)) ∪ [max(4,L_i), i], L_i as derived.
// Softmax WITHOUT max-subtraction (scores bounded, shift-invariant).
// Wave = 16 q-rows × 2048 keys. Block = 4 waves. Grid = 32 bh × 32.
// mfma_f32_16x16x32_bf16: A[m=lane&15][k=quad*8+j]; B[k=quad*8+j][n=lane&15];
// C/D: col=lane&15, row=quad*4+reg.  (m89/m120-verified layouts)
// ---------------------------------------------------------------------------
__global__ __launch_bounds__(256) void attn_mfma(
    const unsigned short* __restrict__ qst,
    const unsigned short* __restrict__ kst,
    const unsigned short* __restrict__ vtT,
    float* __restrict__ attn)
{
    __shared__ unsigned short p_tile[4][16][32];   // 4 KB, per-wave private slice

    const int tid  = threadIdx.x;
    const int wave = tid >> 6;
    const int lane = tid & 63;
    const int col  = lane & 15;
    const int quad = lane >> 4;

    const int bh   = blockIdx.x >> 5;
    const int row0 = (blockIdx.x & 31) * 64 + wave * 16;

    const size_t base = (size_t)bh * SEQ * HDIM;   // qst/kst; vtT same stride

    // Q A-fragments (rows row0..row0+15, k split 0..31 / 32..63)
    const unsigned short* qp = qst + base + (size_t)(row0 + col) * HDIM + quad * 8;
    short8 aq0 = *(const short8*)(qp);
    short8 aq1 = *(const short8*)(qp + 32);

    // per-row mask params for rows quad*4 + r
    int iR[4], ngR[4], j0R[4];
    #pragma unroll
    for (int r = 0; r < 4; ++r) {
        int i = row0 + quad * 4 + r;
        iR[r] = i;
        ngR[r] = (i + 1 < 4) ? (i + 1) : 4;
        int L = i - 128;
        int bs = (i >> 8) << 8;
        if (bs < L) L = bs;
        if (L < 0) L = 0;
        j0R[r] = (L > 4) ? L : 4;
    }

    floatx4 o0 = {0.f, 0.f, 0.f, 0.f}, o1 = o0, o2 = o0, o3 = o0;
    float lsum[4] = {0.f, 0.f, 0.f, 0.f};

    for (int c32 = 0; c32 < SEQ / 32; ++c32) {
        const int kc0 = c32 * 32;
        #pragma unroll
        for (int h16 = 0; h16 < 2; ++h16) {
            const int kc = kc0 + h16 * 16;
            const unsigned short* kp = kst + base + (size_t)(kc + col) * HDIM + quad * 8;
            short8 bk0 = *(const short8*)(kp);
            short8 bk1 = *(const short8*)(kp + 32);
            floatx4 s = {0.f, 0.f, 0.f, 0.f};
            s = __builtin_amdgcn_mfma_f32_16x16x32_bf16(aq0, bk0, s, 0, 0, 0);
            s = __builtin_amdgcn_mfma_f32_16x16x32_bf16(aq1, bk1, s, 0, 0, 0);
            const int j = kc + col;
            #pragma unroll
            for (int r = 0; r < 4; ++r) {
                bool excl = (j < ngR[r]) || (j >= j0R[r] && j <= iR[r]);
                float p = excl ? 0.f : __expf(s[r]);
                unsigned short pb = f2bf(p);
                lsum[r] += bf2f(pb);          // denominator matches numerator's bf16 p
                p_tile[wave][quad * 4 + r][h16 * 16 + col] = pb;
            }
        }
        __syncthreads();   // LDS write->read ordering (uniform across all 4 waves)
        // P A-fragment for PV
        short8 ap = *(const short8*)&p_tile[wave][col][quad * 8];
        // V B-fragments from transposed V: 8 consecutive keys along s
        const unsigned short* vp = vtT + base + (size_t)col * SEQ + kc0 + quad * 8;
        short8 bv0 = *(const short8*)(vp);
        short8 bv1 = *(const short8*)(vp + 16 * SEQ);
        short8 bv2 = *(const short8*)(vp + 32 * SEQ);
        short8 bv3 = *(const short8*)(vp + 48 * SEQ);
        o0 = __builtin_amdgcn_mfma_f32_16x16x32_bf16(ap, bv0, o0, 0, 0, 0);
        o1 = __builtin_amdgcn_mfma_f32_16x16x32_bf16(ap, bv1, o1, 0, 0, 0);
        o2 = __builtin_amdgcn_mfma_f32_16x16x32_bf16(ap, bv2, o2, 0, 0, 0);
        o3 = __builtin_amdgcn_mfma_f32_16x16x32_bf16(ap, bv3, o3, 0, 0, 0);
    }

    // Row sums: lanes sharing (quad,r) hold 16 col-partials -> xor-reduce low 4 bits
    #pragma unroll
    for (int r = 0; r < 4; ++r) {
        float v = lsum[r];
        v += __shfl_xor(v, 1);
        v += __shfl_xor(v, 2);
        v += __shfl_xor(v, 4);
        v += __shfl_xor(v, 8);
        lsum[r] = v;
    }

    const int b = bh >> 4, h = bh & 15;
    #pragma unroll
    for (int r = 0; r < 4; ++r) {
        float inv = 1.0f / lsum[r];
        float* orow = attn + ((size_t)(b * SEQ + iR[r])) * EMBD + h * HDIM + col;
        orow[0]  = o0[r] * inv;
        orow[16] = o1[r] * inv;
        orow[32] = o2[r] * inv;
        orow[48] = o3[r] * inv;
    }
}

// ---------------------------------------------------------------------------
// Kernel 3: out = attn (fp32 4096x1024) @ w_out (fp32 1024x1024) -> fp32
// ---------------------------------------------------------------------------
__global__ __launch_bounds__(256) void gemm_out(
    const float* __restrict__ A,
    const float* __restrict__ w,
    float* __restrict__ out)
{
    __shared__ float As[16][68];
    __shared__ float Bs[16][68];

    const int t  = threadIdx.x;
    const int tx = t & 15;
    const int ty = t >> 4;
    const int n0 = blockIdx.x * 64;
    const int m0 = blockIdx.y * 64;

    const int arow = t >> 2;
    const int acg  = (t & 3) * 4;
    const int brow = t >> 4;
    const int bcg  = (t & 15) * 4;

    float acc[4][4] = {};

    for (int k0 = 0; k0 < EMBD; k0 += 16) {
        float4 a4 = *(const float4*)(A + (size_t)(m0 + arow) * EMBD + k0 + acg);
        As[acg + 0][arow] = a4.x;
        As[acg + 1][arow] = a4.y;
        As[acg + 2][arow] = a4.z;
        As[acg + 3][arow] = a4.w;
        float4 b4 = *(const float4*)(w + (size_t)(k0 + brow) * EMBD + n0 + bcg);
        *(float4*)&Bs[brow][bcg] = b4;
        __syncthreads();
        #pragma unroll
        for (int kk = 0; kk < 16; ++kk) {
            float4 a = *(const float4*)&As[kk][ty * 4];
            float4 b = *(const float4*)&Bs[kk][tx * 4];
            float av[4] = {a.x, a.y, a.z, a.w};
            float bv[4] = {b.x, b.y, b.z, b.w};
            #pragma unroll
            for (int i = 0; i < 4; ++i)
                #pragma unroll
                for (int j = 0; j < 4; ++j)
                    acc[i][j] += av[i] * bv[j];
        }
        __syncthreads();
    }

    #pragma unroll
    for (int i = 0; i < 4; ++i) {
        int m = m0 + ty * 4 + i;
        float4 o;
        o.x = acc[i][0]; o.y = acc[i][1]; o.z = acc[i][2]; o.w = acc[i][3];
        *(float4*)(out + (size_t)m * EMBD + n0 + tx * 4) = o;
    }
}

// ---------------------------------------------------------------------------
extern "C" void kernel_launch(void* const* d_in, const int* in_sizes, int n_in,
                              void* d_out, int out_size, void* d_ws, size_t ws_size,
                              hipStream_t stream) {
    const float* x     = (const float*)d_in[0];  // (2,2048,1024)
    const float* w_qkv = (const float*)d_in[1];  // (1024,3072)
    const float* w_out = (const float*)d_in[2];  // (1024,1024)
    float* out = (float*)d_out;                  // (2,2048,1024)

    // Workspace (40 MB used; 64 MB proven available in R7):
    unsigned short* ws16 = (unsigned short*)d_ws;
    unsigned short* qst = ws16;                      // bf16 [bh][s][d]  8 MB
    unsigned short* kst = ws16 + 4194304;            // bf16 [bh][s][d]  8 MB
    unsigned short* vtT = ws16 + 8388608;            // bf16 [bh][d][s]  8 MB
    float*          aws = (float*)(ws16 + 12582912); // fp32 (B,S,E)    16 MB

    dim3 blk(256);
    dim3 g1(NQKV / 64, MROWS / 64);     // (48, 64)
    gemm_qkv_rope<<<g1, blk, 0, stream>>>(x, w_qkv, qst, kst, vtT);

    attn_mfma<<<dim3(32 * 32), blk, 0, stream>>>(qst, kst, vtT, aws);

    dim3 g2(EMBD / 64, MROWS / 64);     // (16, 64)
    gemm_out<<<g2, blk, 0, stream>>>(aws, w_out, out);
}

// Round 9
// 611.993 us; speedup vs baseline: 8.4828x; 1.2347x over previous
//
#include <hip/hip_runtime.h>
#include <hip/hip_bf16.h>

// Problem constants
#define EMBD   1024
#define NHEAD  16
#define HDIM   64
#define SEQ    2048
#define BATCH  2
#define MROWS  4096          // BATCH*SEQ
#define NQKV   3072          // 3*EMBD

using floatx4 = __attribute__((ext_vector_type(4))) float;
using short8  = __attribute__((ext_vector_type(8))) short;

static __device__ __forceinline__ float bf2f(unsigned short u) {
    unsigned int v = ((unsigned int)u) << 16;
    return __uint_as_float(v);
}
static __device__ __forceinline__ unsigned short f2bf(float f) {
    __hip_bfloat16 h = __float2bfloat16(f);   // RNE
    return *reinterpret_cast<unsigned short*>(&h);
}

// async 16B global->LDS (m97 pattern; LDS dest is wave-uniform base + lane*16)
static __device__ __forceinline__ void stage16(const unsigned short* g, unsigned short* l) {
    __builtin_amdgcn_global_load_lds(
        (const __attribute__((address_space(1))) unsigned int*)g,
        (__attribute__((address_space(3))) unsigned int*)l, 16, 0, 0);
}

// ---------------------------------------------------------------------------
// Cast kernels: fp32 -> split bf16 (hi + lo), w transposed to [N][K].
// ---------------------------------------------------------------------------
__global__ __launch_bounds__(256) void cast_x(
    const float* __restrict__ x, unsigned short* __restrict__ xh,
    unsigned short* __restrict__ xl)
{
    int idx = (blockIdx.x * 256 + threadIdx.x) * 4;
    float4 v = *(const float4*)(x + idx);
    ushort4 h, l;
    h.x = f2bf(v.x); l.x = f2bf(v.x - bf2f(h.x));
    h.y = f2bf(v.y); l.y = f2bf(v.y - bf2f(h.y));
    h.z = f2bf(v.z); l.z = f2bf(v.z - bf2f(h.z));
    h.w = f2bf(v.w); l.w = f2bf(v.w - bf2f(h.w));
    *(ushort4*)(xh + idx) = h;
    *(ushort4*)(xl + idx) = l;
}

// w [1024][N] fp32 -> wT_h/wT_l [N][1024] bf16 (64x64 LDS-tiled transpose)
__global__ __launch_bounds__(256) void cast_wT(
    const float* __restrict__ w, unsigned short* __restrict__ wT_h,
    unsigned short* __restrict__ wT_l, int N, int withLo)
{
    __shared__ unsigned short th[64][65];
    __shared__ unsigned short tl[64][65];
    const int k0 = blockIdx.y * 64, n0 = blockIdx.x * 64;
    const int t = threadIdx.x;
    const int r = t >> 4, c = (t & 15) * 4;
    for (int rr = r; rr < 64; rr += 16) {
        float4 v = *(const float4*)(w + (size_t)(k0 + rr) * N + n0 + c);
        unsigned short h0 = f2bf(v.x), h1 = f2bf(v.y), h2 = f2bf(v.z), h3 = f2bf(v.w);
        th[rr][c + 0] = h0; tl[rr][c + 0] = f2bf(v.x - bf2f(h0));
        th[rr][c + 1] = h1; tl[rr][c + 1] = f2bf(v.y - bf2f(h1));
        th[rr][c + 2] = h2; tl[rr][c + 2] = f2bf(v.z - bf2f(h2));
        th[rr][c + 3] = h3; tl[rr][c + 3] = f2bf(v.w - bf2f(h3));
    }
    __syncthreads();
    for (int rr = r; rr < 64; rr += 16) {
        ushort4 h;
        h.x = th[c + 0][rr]; h.y = th[c + 1][rr];
        h.z = th[c + 2][rr]; h.w = th[c + 3][rr];
        *(ushort4*)(wT_h + (size_t)(n0 + rr) * 1024 + k0 + c) = h;
        if (withLo) {
            ushort4 l;
            l.x = tl[c + 0][rr]; l.y = tl[c + 1][rr];
            l.z = tl[c + 2][rr]; l.w = tl[c + 3][rr];
            *(ushort4*)(wT_l + (size_t)(n0 + rr) * 1024 + k0 + c) = l;
        }
    }
}

// ---------------------------------------------------------------------------
// Kernel: qkv = x @ w_qkv via split-bf16 MFMA (hh + hl + lh), fused RoPE.
// 128x128 tile, BK=32, 4 waves (each 64x64). global_load_lds staging.
// q/k: operand-swapped MFMA (acc = C^T) so lane regs = 4 consecutive d at
// fixed s -> in-lane RoPE pairs + 8B stores into [bh][s][d].
// v: normal orientation -> lane regs = 4 consecutive s at fixed d -> 8B
// stores into transposed [bh][d][s].
// ---------------------------------------------------------------------------
__global__ __launch_bounds__(256) void gemm_qkv_mfma(
    const unsigned short* __restrict__ xh, const unsigned short* __restrict__ xl,
    const unsigned short* __restrict__ whT, const unsigned short* __restrict__ wlT,
    unsigned short* __restrict__ qst, unsigned short* __restrict__ kst,
    unsigned short* __restrict__ vtT)
{
    __shared__ unsigned short smem[16384];   // 32 KB: 4 tiles [128][32]
    unsigned short* sXH = smem;
    unsigned short* sXL = smem + 4096;
    unsigned short* sWH = smem + 8192;
    unsigned short* sWL = smem + 12288;

    const int t = threadIdx.x, wave = t >> 6, lane = t & 63;
    const int col = lane & 15, quad = lane >> 4;
    const int n0 = blockIdx.x * 128;
    const int m0 = blockIdx.y * 128;
    const int which = n0 >> 10;              // block-uniform: 0=q,1=k,2=v
    const int wm = (wave >> 1) * 64, wn = (wave & 1) * 64;

    const int srow = lane >> 2;              // staging row within 16-row slab
    const int scol = (lane & 3) * 8;         // staging k-offset (elems)

    floatx4 acc[4][4];
    #pragma unroll
    for (int i = 0; i < 4; ++i)
        #pragma unroll
        for (int j = 0; j < 4; ++j) acc[i][j] = (floatx4){0.f, 0.f, 0.f, 0.f};

    const unsigned short* gx_h = xh + (size_t)m0 * 1024;
    const unsigned short* gx_l = xl + (size_t)m0 * 1024;
    const unsigned short* gw_h = whT + (size_t)n0 * 1024;
    const unsigned short* gw_l = wlT + (size_t)n0 * 1024;

    for (int k0 = 0; k0 < 1024; k0 += 32) {
        __syncthreads();
        #pragma unroll
        for (int hh = 0; hh < 2; ++hh) {
            const int rbase = hh * 64 + wave * 16;        // wave-uniform
            const size_t go = (size_t)(rbase + srow) * 1024 + k0 + scol;
            const int lo = rbase * 32;                    // wave-uniform LDS elem offset
            stage16(gx_h + go, sXH + lo);
            stage16(gx_l + go, sXL + lo);
            stage16(gw_h + go, sWH + lo);
            stage16(gw_l + go, sWL + lo);
        }
        __syncthreads();

        short8 ah[4], al[4], bh[4], bl[4];
        #pragma unroll
        for (int f = 0; f < 4; ++f) {
            ah[f] = *(const short8*)&sXH[(wm + f * 16 + col) * 32 + quad * 8];
            al[f] = *(const short8*)&sXL[(wm + f * 16 + col) * 32 + quad * 8];
            bh[f] = *(const short8*)&sWH[(wn + f * 16 + col) * 32 + quad * 8];
            bl[f] = *(const short8*)&sWL[(wn + f * 16 + col) * 32 + quad * 8];
        }
        if (which < 2) {
            #pragma unroll
            for (int fm = 0; fm < 4; ++fm)
                #pragma unroll
                for (int fn = 0; fn < 4; ++fn) {
                    floatx4 c = acc[fm][fn];               // C^T orientation
                    c = __builtin_amdgcn_mfma_f32_16x16x32_bf16(bh[fn], ah[fm], c, 0, 0, 0);
                    c = __builtin_amdgcn_mfma_f32_16x16x32_bf16(bh[fn], al[fm], c, 0, 0, 0);
                    c = __builtin_amdgcn_mfma_f32_16x16x32_bf16(bl[fn], ah[fm], c, 0, 0, 0);
                    acc[fm][fn] = c;
                }
        } else {
            #pragma unroll
            for (int fm = 0; fm < 4; ++fm)
                #pragma unroll
                for (int fn = 0; fn < 4; ++fn) {
                    floatx4 c = acc[fm][fn];               // normal orientation
                    c = __builtin_amdgcn_mfma_f32_16x16x32_bf16(ah[fm], bh[fn], c, 0, 0, 0);
                    c = __builtin_amdgcn_mfma_f32_16x16x32_bf16(al[fm], bh[fn], c, 0, 0, 0);
                    c = __builtin_amdgcn_mfma_f32_16x16x32_bf16(ah[fm], bl[fn], c, 0, 0, 0);
                    acc[fm][fn] = c;
                }
        }
    }

    const float RLOG = 9.210340371976184f / 32.0f;   // ln(10000)/32
    if (which < 2) {
        unsigned short* dst = (which == 0) ? qst : kst;
        const float scale = (which == 0) ? 0.125f : 1.0f;   // D^-0.5 folded into q
        #pragma unroll
        for (int fm = 0; fm < 4; ++fm) {
            const int s_g = m0 + wm + fm * 16 + col;     // D-col = x row = s
            const int b = s_g >> 11, s = s_g & 2047;
            const float sf = (float)s;
            #pragma unroll
            for (int fn = 0; fn < 4; ++fn) {
                const int nl = (n0 & 1023) + wn + fn * 16 + quad * 4;  // D-row = w col
                const int h = nl >> 6;
                const int d0 = nl & 63;                  // multiple of 4
                floatx4 c = acc[fm][fn];
                float o_[4];
                #pragma unroll
                for (int pp = 0; pp < 2; ++pp) {
                    int de = d0 + pp * 2;                // even
                    float fe = __expf(-(float)(de & 31) * RLOG);
                    float fo = __expf(-(float)((de + 1) & 31) * RLOG);
                    float se, ce, so, co;
                    sincosf(sf * fe, &se, &ce);
                    sincosf(sf * fo, &so, &co);
                    float qe = c[pp * 2], qo = c[pp * 2 + 1];
                    o_[pp * 2]     = (qe * ce - qo * se) * scale;
                    o_[pp * 2 + 1] = (qo * co + qe * so) * scale;
                }
                ushort4 o4;
                o4.x = f2bf(o_[0]); o4.y = f2bf(o_[1]);
                o4.z = f2bf(o_[2]); o4.w = f2bf(o_[3]);
                *(ushort4*)(dst + ((size_t)(b * 16 + h) * 2048 + s) * 64 + d0) = o4;
            }
        }
    } else {
        #pragma unroll
        for (int fm = 0; fm < 4; ++fm) {
            const int m = m0 + wm + fm * 16 + quad * 4;  // 4 consecutive s (regs)
            const int b = m >> 11, s0 = m & 2047;
            #pragma unroll
            for (int fn = 0; fn < 4; ++fn) {
                const int nl = (n0 & 1023) + wn + fn * 16 + col;
                const int h = nl >> 6;
                const int d = nl & 63;
                floatx4 c = acc[fm][fn];
                ushort4 o4;
                o4.x = f2bf(c[0]); o4.y = f2bf(c[1]);
                o4.z = f2bf(c[2]); o4.w = f2bf(c[3]);
                *(ushort4*)(vtT + ((size_t)(b * 16 + h) * 64 + d) * 2048 + s0) = o4;
            }
        }
    }
}

// ---------------------------------------------------------------------------
// Attention: complement-masked, bf16 MFMA, single pass (R8-verified).
// Output now bf16 [M][E] for the MFMA output projection.
// ---------------------------------------------------------------------------
__global__ __launch_bounds__(256) void attn_mfma(
    const unsigned short* __restrict__ qst,
    const unsigned short* __restrict__ kst,
    const unsigned short* __restrict__ vtT,
    unsigned short* __restrict__ attn)
{
    __shared__ unsigned short p_tile[4][16][32];

    const int tid  = threadIdx.x;
    const int wave = tid >> 6;
    const int lane = tid & 63;
    const int col  = lane & 15;
    const int quad = lane >> 4;

    const int bh   = blockIdx.x >> 5;
    const int row0 = (blockIdx.x & 31) * 64 + wave * 16;

    const size_t base = (size_t)bh * SEQ * HDIM;

    const unsigned short* qp = qst + base + (size_t)(row0 + col) * HDIM + quad * 8;
    short8 aq0 = *(const short8*)(qp);
    short8 aq1 = *(const short8*)(qp + 32);

    int iR[4], ngR[4], j0R[4];
    #pragma unroll
    for (int r = 0; r < 4; ++r) {
        int i = row0 + quad * 4 + r;
        iR[r] = i;
        ngR[r] = (i + 1 < 4) ? (i + 1) : 4;
        int L = i - 128;
        int bs = (i >> 8) << 8;
        if (bs < L) L = bs;
        if (L < 0) L = 0;
        j0R[r] = (L > 4) ? L : 4;
    }

    floatx4 o0 = {0.f, 0.f, 0.f, 0.f}, o1 = o0, o2 = o0, o3 = o0;
    float lsum[4] = {0.f, 0.f, 0.f, 0.f};

    for (int c32 = 0; c32 < SEQ / 32; ++c32) {
        const int kc0 = c32 * 32;
        #pragma unroll
        for (int h16 = 0; h16 < 2; ++h16) {
            const int kc = kc0 + h16 * 16;
            const unsigned short* kp = kst + base + (size_t)(kc + col) * HDIM + quad * 8;
            short8 bk0 = *(const short8*)(kp);
            short8 bk1 = *(const short8*)(kp + 32);
            floatx4 s = {0.f, 0.f, 0.f, 0.f};
            s = __builtin_amdgcn_mfma_f32_16x16x32_bf16(aq0, bk0, s, 0, 0, 0);
            s = __builtin_amdgcn_mfma_f32_16x16x32_bf16(aq1, bk1, s, 0, 0, 0);
            const int j = kc + col;
            #pragma unroll
            for (int r = 0; r < 4; ++r) {
                bool excl = (j < ngR[r]) || (j >= j0R[r] && j <= iR[r]);
                float p = excl ? 0.f : __expf(s[r]);
                unsigned short pb = f2bf(p);
                lsum[r] += bf2f(pb);
                p_tile[wave][quad * 4 + r][h16 * 16 + col] = pb;
            }
        }
        __syncthreads();
        short8 ap = *(const short8*)&p_tile[wave][col][quad * 8];
        const unsigned short* vp = vtT + base + (size_t)col * SEQ + kc0 + quad * 8;
        short8 bv0 = *(const short8*)(vp);
        short8 bv1 = *(const short8*)(vp + 16 * SEQ);
        short8 bv2 = *(const short8*)(vp + 32 * SEQ);
        short8 bv3 = *(const short8*)(vp + 48 * SEQ);
        o0 = __builtin_amdgcn_mfma_f32_16x16x32_bf16(ap, bv0, o0, 0, 0, 0);
        o1 = __builtin_amdgcn_mfma_f32_16x16x32_bf16(ap, bv1, o1, 0, 0, 0);
        o2 = __builtin_amdgcn_mfma_f32_16x16x32_bf16(ap, bv2, o2, 0, 0, 0);
        o3 = __builtin_amdgcn_mfma_f32_16x16x32_bf16(ap, bv3, o3, 0, 0, 0);
    }

    #pragma unroll
    for (int r = 0; r < 4; ++r) {
        float v = lsum[r];
        v += __shfl_xor(v, 1);
        v += __shfl_xor(v, 2);
        v += __shfl_xor(v, 4);
        v += __shfl_xor(v, 8);
        lsum[r] = v;
    }

    const int b = bh >> 4, h = bh & 15;
    #pragma unroll
    for (int r = 0; r < 4; ++r) {
        float inv = 1.0f / lsum[r];
        unsigned short* orow = attn + ((size_t)(b * SEQ + iR[r])) * EMBD + h * HDIM + col;
        orow[0]  = f2bf(o0[r] * inv);
        orow[16] = f2bf(o1[r] * inv);
        orow[32] = f2bf(o2[r] * inv);
        orow[48] = f2bf(o3[r] * inv);
    }
}

// ---------------------------------------------------------------------------
// Output projection: out = attn(bf16) @ w_out via 1-pass bf16 MFMA -> fp32.
// ---------------------------------------------------------------------------
__global__ __launch_bounds__(256) void gemm_out_mfma(
    const unsigned short* __restrict__ A,      // [4096][1024] bf16
    const unsigned short* __restrict__ woT,    // [1024 n][1024 k] bf16
    float* __restrict__ out)
{
    __shared__ unsigned short smem[8192];      // 16 KB: 2 tiles [128][32]
    unsigned short* sA = smem;
    unsigned short* sB = smem + 4096;

    const int t = threadIdx.x, wave = t >> 6, lane = t & 63;
    const int col = lane & 15, quad = lane >> 4;
    const int n0 = blockIdx.x * 128;
    const int m0 = blockIdx.y * 128;
    const int wm = (wave >> 1) * 64, wn = (wave & 1) * 64;
    const int srow = lane >> 2;
    const int scol = (lane & 3) * 8;

    floatx4 acc[4][4];
    #pragma unroll
    for (int i = 0; i < 4; ++i)
        #pragma unroll
        for (int j = 0; j < 4; ++j) acc[i][j] = (floatx4){0.f, 0.f, 0.f, 0.f};

    const unsigned short* gA = A   + (size_t)m0 * 1024;
    const unsigned short* gB = woT + (size_t)n0 * 1024;

    for (int k0 = 0; k0 < 1024; k0 += 32) {
        __syncthreads();
        #pragma unroll
        for (int hh = 0; hh < 2; ++hh) {
            const int rbase = hh * 64 + wave * 16;
            const size_t go = (size_t)(rbase + srow) * 1024 + k0 + scol;
            const int lo = rbase * 32;
            stage16(gA + go, sA + lo);
            stage16(gB + go, sB + lo);
        }
        __syncthreads();

        short8 af[4], bf4[4];
        #pragma unroll
        for (int f = 0; f < 4; ++f) {
            af[f]  = *(const short8*)&sA[(wm + f * 16 + col) * 32 + quad * 8];
            bf4[f] = *(const short8*)&sB[(wn + f * 16 + col) * 32 + quad * 8];
        }
        #pragma unroll
        for (int fm = 0; fm < 4; ++fm)
            #pragma unroll
            for (int fn = 0; fn < 4; ++fn)
                acc[fm][fn] = __builtin_amdgcn_mfma_f32_16x16x32_bf16(
                    af[fm], bf4[fn], acc[fm][fn], 0, 0, 0);
    }

    #pragma unroll
    for (int fm = 0; fm < 4; ++fm) {
        const int m = m0 + wm + fm * 16 + quad * 4;
        #pragma unroll
        for (int fn = 0; fn < 4; ++fn) {
            const int n = n0 + wn + fn * 16 + col;
            floatx4 c = acc[fm][fn];
            out[(size_t)(m + 0) * 1024 + n] = c[0];
            out[(size_t)(m + 1) * 1024 + n] = c[1];
            out[(size_t)(m + 2) * 1024 + n] = c[2];
            out[(size_t)(m + 3) * 1024 + n] = c[3];
        }
    }
}

// ---------------------------------------------------------------------------
extern "C" void kernel_launch(void* const* d_in, const int* in_sizes, int n_in,
                              void* d_out, int out_size, void* d_ws, size_t ws_size,
                              hipStream_t stream) {
    const float* x     = (const float*)d_in[0];  // (2,2048,1024)
    const float* w_qkv = (const float*)d_in[1];  // (1024,3072)
    const float* w_out = (const float*)d_in[2];  // (1024,1024)
    float* out = (float*)d_out;                  // (2,2048,1024)

    // Workspace map (bf16 elems; total 65.0 MB of the proven >=64 MiB):
    unsigned short* ws16 = (unsigned short*)d_ws;
    unsigned short* xh  = ws16;              // 4,194,304
    unsigned short* xl  = ws16 +  4194304;   // 4,194,304
    unsigned short* whT = ws16 +  8388608;   // 3,145,728  [3072][1024]
    unsigned short* wlT = ws16 + 11534336;   // 3,145,728
    unsigned short* woT = ws16 + 14680064;   // 1,048,576  [1024][1024]
    unsigned short* qst = ws16 + 15728640;   // 4,194,304  [bh][s][d]
    unsigned short* kst = ws16 + 19922944;   // 4,194,304  [bh][s][d]
    unsigned short* vtT = ws16 + 24117248;   // 4,194,304  [bh][d][s]
    unsigned short* aws = ws16 + 28311552;   // 4,194,304  [M][E] bf16

    dim3 blk(256);
    cast_x<<<dim3(4096), blk, 0, stream>>>(x, xh, xl);
    cast_wT<<<dim3(48, 16), blk, 0, stream>>>(w_qkv, whT, wlT, NQKV, 1);
    cast_wT<<<dim3(16, 16), blk, 0, stream>>>(w_out, woT, woT, EMBD, 0);

    gemm_qkv_mfma<<<dim3(NQKV / 128, MROWS / 128), blk, 0, stream>>>(
        xh, xl, whT, wlT, qst, kst, vtT);

    attn_mfma<<<dim3(32 * 32), blk, 0, stream>>>(qst, kst, vtT, aws);

    gemm_out_mfma<<<dim3(EMBD / 128, MROWS / 128), blk, 0, stream>>>(aws, woT, out);
}